// Round 8
// baseline (198.645 us; speedup 1.0000x reference)
//
#include <hip/hip_runtime.h>

// PatchEncoder fused kernel, round 10: per-wave double-buffered pipeline.
// out[b, (h/16)*32 + w/16, (h%16)*48 + (w%16)*3 + c]
//   = conv3x3_SAME(X)[b,h,w,c] + bias[c]
//     + pos_emb[(h/4)*128 + (w/4), (h%4)*12 + (w%4)*3 + c]
//
// History: R4 69us (barriers), R6 63.7us, R8 75.4us (more occupancy,
// slower), R9 71-75us (ZERO barriers, same speed). Every variant sits at
// 64-75us with all pipes ~30%: the wave lifecycle is serial
// (DMA -> full HBM wait -> compute with empty VMEM queue -> drain), and
// 2.5-4 waves/SIMD of TLP can't cover the holes. VALU issue is only
// ~46k cyc/CU -> a fully-overlapped kernel runs ~20-30us.
//
// R10: pipeline WITHIN the wave (ILP, not TLP):
//  - grid 8x2x32 = 512 blocks (2/CU); block = 4 waves; wave owns a
//    64-wide strip and loops 8 steps x 8 rows down a 256-row half.
//  - per wave: 2 x 2048-float LDS buffers (16KB); block 64KB.
//  - step t: vmcnt(0)-wait for buf[t&1] (prefetched LAST step, in
//    flight through the whole previous compute) -> issue step t+1's
//    8 DMAs into buf[(t+1)&1] -> fixup/compute/outstage/drain buf[t&1].
//    Only exposure: prologue once + residual store latency per step.
//  - zero __syncthreads (R9 wave-autonomy); R8's verified flat
//    stride-200 DMA addressing; R9's verified outstage/drain.
//  - occupancy cap 8 waves/CU (25%) is EXPECTED: latency hiding now
//    comes from the loads-in-flight-during-compute, not wave count.

#define BATCH 32
#define IMH 512
#define IMW 512
#define RSF 200            // input row stride, floats
#define BUF 2048           // floats per buffer (8 DMAs x 256)
#define WREG 4096          // floats per wave (2 buffers)
#define OPST 392           // out-stage patch stride, floats
#define NSTEP 8

__device__ __forceinline__ void dma16(const float* g, float* l) {
    __builtin_amdgcn_global_load_lds(
        (const __attribute__((address_space(1))) void*)g,
        (__attribute__((address_space(3))) void*)l,
        16, 0, 0);
}

__global__ __launch_bounds__(256, 2) void patch_enc_kernel(
    const float* __restrict__ X,     // [B,H,W,3] NHWC
    const float* __restrict__ Kw,    // [3,3,3,3] HWIO
    const float* __restrict__ bias,  // [3]
    const float* __restrict__ pos,   // [16384,48]
    float* __restrict__ out)         // [B,1024,768]
{
    __shared__ float lds[4 * WREG];   // 64 KB -> 2 blocks/CU

    const int tid  = threadIdx.x;
    const int lane = tid & 63;
    const int wv   = tid >> 6;
    const int w0   = blockIdx.x * 64;
    const int half = blockIdx.y;
    const int b    = blockIdx.z;

    const bool lEdge = (w0 == 0);
    const bool rEdge = (w0 == IMW - 64);

    float* const buf0 = &lds[wv * WREG];
    float* const buf1 = buf0 + BUF;

    const float* Xb  = X + (size_t)b * (IMH * IMW * 3);
    const float* xlo = X;
    const float* xhi = X + (size_t)BATCH * IMH * IMW * 3 - 4;  // last 16B start

    // weights/bias: uniform -> s_load -> SGPR operands
    float wk[81];
#pragma unroll
    for (int i = 0; i < 81; ++i) wk[i] = Kw[i];
    const float bs0 = bias[0], bs1 = bias[1], bs2 = bias[2];

    const int g  = lane & 15;
    const int r2 = lane >> 4;

    // step-invariant per-lane DMA offsets: buffer float f = 256d+4*lane
    // <-> row f/200, col o=f%200; global offset row*1536 + o.
    int off[8];
#pragma unroll
    for (int d = 0; d < 8; ++d) {
        const int f   = 256 * d + 4 * lane;
        const int row = f / 200;
        const int o   = f - 200 * row;
        off[d] = row * (IMW * 3) + o;
    }

    const int hs0 = half * 256 + wv * 8;   // wave's step-0 strip start row

    // ---- STAGE: issue 8 16B DMAs for strip hs into buf ----
    auto STAGE = [&](float* buf, int hs) {
        const float* Xt = Xb + (long)(hs - 1) * (IMW * 3) + (3 * w0 - 4);
#pragma unroll
        for (int d = 0; d < 8; ++d) {
            const float* gp = Xt + off[d];
            gp = (gp < xlo) ? xlo : gp;    // always-clamp: 2 cndmask, no branch
            gp = (gp > xhi) ? xhi : gp;
            dma16(gp, &buf[256 * d]);
        }
    };

    // ---- PROCESS: fixup + conv + epilogue + outstage + drain for strip hs ----
    auto PROCESS = [&](float* buf, int hs) {
        // zero-pad fixups (wave-uniform conds except lane<10)
        if (hs == 0)         for (int j = lane; j < RSF; j += 64) buf[j] = 0.0f;
        if (hs == IMH - 8)   for (int j = lane; j < RSF; j += 64) buf[9 * RSF + j] = 0.0f;
        if (lEdge && lane < 10) {
            float* p = &buf[lane * RSF];
            p[1] = 0.0f; p[2] = 0.0f; p[3] = 0.0f;            // col w=-1
        }
        if (rEdge && lane < 10) {
            float* p = &buf[lane * RSF + 196];
            p[0] = 0.0f; p[1] = 0.0f; p[2] = 0.0f;            // col w=512
        }

        float acc0[12], acc1[12];
#pragma unroll
        for (int i = 0; i < 12; ++i) { acc0[i] = 0.0f; acc1[i] = 0.0f; }

        // buffer row (2*r2+q): out-row0 needs weight-row q (q<=2),
        // out-row1 weight-row q-1 (q>=1). 4 rows read for 2 computed.
#pragma unroll
        for (int q = 0; q < 4; ++q) {
            const float* bp = &buf[(2 * r2 + q) * RSF + 12 * g];
            float s[20];
#pragma unroll
            for (int j = 0; j < 5; ++j)
                *(float4*)&s[4 * j] = *(const float4*)(bp + 4 * j);   // ds_read_b128
#pragma unroll
            for (int dc = 0; dc < 3; ++dc)
#pragma unroll
            for (int ci = 0; ci < 3; ++ci) {
#pragma unroll
                for (int i = 0; i < 4; ++i) {
                    const float x = s[3 * (i + dc) + ci + 1];
                    if (q <= 2) {
                        const float* wp = &wk[((q * 3 + dc) * 3 + ci) * 3];
                        acc0[i * 3 + 0] = fmaf(x, wp[0], acc0[i * 3 + 0]);
                        acc0[i * 3 + 1] = fmaf(x, wp[1], acc0[i * 3 + 1]);
                        acc0[i * 3 + 2] = fmaf(x, wp[2], acc0[i * 3 + 2]);
                    }
                    if (q >= 1) {
                        const float* wp = &wk[(((q - 1) * 3 + dc) * 3 + ci) * 3];
                        acc1[i * 3 + 0] = fmaf(x, wp[0], acc1[i * 3 + 0]);
                        acc1[i * 3 + 1] = fmaf(x, wp[1], acc1[i * 3 + 1]);
                        acc1[i * 3 + 2] = fmaf(x, wp[2], acc1[i * 3 + 2]);
                    }
                }
            }
        }

        // bias + pos_emb (rows share n: one 96B contiguous load)
        const int hg0 = hs + 2 * r2;
        const int wg0 = w0 + 4 * g;
        const int n   = (hg0 >> 2) * 128 + (wg0 >> 2);
        const float* pp = pos + (size_t)n * 48 + (hg0 & 3) * 12;   // 16B aligned
        float pr[24];
#pragma unroll
        for (int j = 0; j < 6; ++j)
            *(float4*)&pr[4 * j] = *(const float4*)(pp + 4 * j);

        float v0[12], v1[12];
#pragma unroll
        for (int k = 0; k < 12; ++k) {
            const float bsk = (k % 3 == 0) ? bs0 : (k % 3 == 1) ? bs1 : bs2;
            v0[k] = acc0[k] + bsk + pr[k];
            v1[k] = acc1[k] + bsk + pr[12 + k];
        }

        // outstage overlays THIS buffer (WAR-safe: FMA deps forced all
        // ds_read completions; buffer not re-DMA'd until step+2)
        {
            const int p  = g >> 2;                            // local patch 0..3
            const int o0 = p * OPST + (2 * r2) * 48 + (g & 3) * 12;
            *(float4*)&buf[o0 + 0] = make_float4(v0[0], v0[1], v0[2],  v0[3]);
            *(float4*)&buf[o0 + 4] = make_float4(v0[4], v0[5], v0[6],  v0[7]);
            *(float4*)&buf[o0 + 8] = make_float4(v0[8], v0[9], v0[10], v0[11]);
            const int o1 = o0 + 48;
            *(float4*)&buf[o1 + 0] = make_float4(v1[0], v1[1], v1[2],  v1[3]);
            *(float4*)&buf[o1 + 4] = make_float4(v1[4], v1[5], v1[6],  v1[7]);
            *(float4*)&buf[o1 + 8] = make_float4(v1[8], v1[9], v1[10], v1[11]);
        }
        asm volatile("s_waitcnt lgkmcnt(0)" ::: "memory");   // ds_writes landed
        __builtin_amdgcn_sched_barrier(0);

        // drain: 4 half-patches, contiguous 1536B runs
        {
            float* outw = out + (size_t)b * 786432
                        + (size_t)((hs >> 4) * 32 + (w0 >> 4)) * 768
                        + (hs & 15) * 48;
#pragma unroll
            for (int c = 0; c < 6; ++c) {
                const int fl  = 4 * lane + 256 * c;     // 0..1535
                const int p   = fl / 384;               // exact const-div
                const int rem = fl - 384 * p;
                const float4 val = *(const float4*)&buf[p * OPST + rem];
                *(float4*)(outw + p * 768 + rem) = val;
            }
        }
    };

    // ---- pipeline ----
    STAGE(buf0, hs0);                                  // prologue
    asm volatile("s_waitcnt vmcnt(0)" ::: "memory");
    __builtin_amdgcn_sched_barrier(0);
    STAGE(buf1, hs0 + 32);                             // prefetch step 1
    PROCESS(buf0, hs0);                                // overlaps prefetch

    for (int step = 1; step < NSTEP; ++step) {
        const int hs = hs0 + step * 32;
        asm volatile("s_waitcnt vmcnt(0)" ::: "memory");   // buf[step&1] landed
        __builtin_amdgcn_sched_barrier(0);
        float* cb = (step & 1) ? buf1 : buf0;
        float* nb = (step & 1) ? buf0 : buf1;
        if (step < NSTEP - 1) STAGE(nb, hs + 32);      // prefetch next, overlaps
        PROCESS(cb, hs);
    }
}

extern "C" void kernel_launch(void* const* d_in, const int* in_sizes, int n_in,
                              void* d_out, int out_size, void* d_ws, size_t ws_size,
                              hipStream_t stream) {
    const float* X    = (const float*)d_in[0];
    const float* Kw   = (const float*)d_in[1];
    const float* bias = (const float*)d_in[2];
    const float* pos  = (const float*)d_in[3];
    float* out = (float*)d_out;

    dim3 grid(IMW / 64, 2, BATCH);   // 8 x 2 x 32 = 512 blocks, 2/CU
    patch_enc_kernel<<<grid, 256, 0, stream>>>(X, Kw, bias, pos, out);
}